// Round 4
// baseline (201.865 us; speedup 1.0000x reference)
//
#include <hip/hip_runtime.h>

#define EPS 1e-5f

__device__ __forceinline__ int reflect_idx(int i, int n) {
    if (i < 0) return -i;
    if (i >= n) return 2 * n - 2 - i;
    return i;
}

__device__ __forceinline__ float bilin(const float* __restrict__ pb, int Hp, float sy, float sx) {
    int y0 = (int)floorf(sy), x0 = (int)floorf(sx);
    float fy = sy - y0, fx = sx - x0;
    int y0c = min(max(y0, 0), Hp - 1), y1c = min(max(y0 + 1, 0), Hp - 1);
    int x0c = min(max(x0, 0), Hp - 1), x1c = min(max(x0 + 1, 0), Hp - 1);
    float v00 = pb[y0c * Hp + x0c], v01 = pb[y0c * Hp + x1c];
    float v10 = pb[y1c * Hp + x0c], v11 = pb[y1c * Hp + x1c];
    return v00 * (1 - fy) * (1 - fx) + v01 * (1 - fy) * fx
         + v10 * fy * (1 - fx) + v11 * fy * fx;
}

// ---------------- Fused build + depthwise 3x3 + striped stats ----------------
// WRITE=false -> stats-only pass (no output store).
template <int LEVEL, bool WRITE>
__global__ __launch_bounds__(256)
void fused_dw_kernel(const float* __restrict__ feat, const float* __restrict__ prev,
                     const float* __restrict__ pss, const float* __restrict__ wsig,
                     float* __restrict__ out, float* __restrict__ part) {
    constexpr int C    = LEVEL == 0 ? 66 : LEVEL == 1 ? 98 : 37;
    constexpr int H    = LEVEL == 0 ? 32 : LEVEL == 1 ? 64 : 256;
    constexpr int TILE = LEVEL == 2 ? 32 : 16;
    constexpr int NT   = H / TILE;
    constexpr int PXPT = (TILE * TILE) / 256;
    constexpr int WC   = LEVEL == 0 ? 4818 : LEVEL == 1 ? 4018 : 1110;
    constexpr int NF   = LEVEL == 0 ? 64 : LEVEL == 1 ? 32 : 3;
    constexpr int Hp   = LEVEL == 1 ? 32 : 64;
    constexpr int Cp   = LEVEL == 1 ? 64 : 32;
    constexpr int P    = H / 8;
    constexpr float SC = LEVEL == 1 ? 0.5f : 0.25f;
    constexpr int HS   = TILE + 2;

    __shared__ float sh[HS * HS];
    int tid = threadIdx.x, bid = blockIdx.x;
    int tile = bid % (NT * NT);
    int c = (bid / (NT * NT)) % C;
    int b = bid / (NT * NT * C);
    int ty0 = (tile / NT) * TILE, tx0 = (tile % NT) * TILE;

    for (int i = tid; i < HS * HS; i += 256) {
        int h = reflect_idx(ty0 - 1 + i / HS, H);
        int w = reflect_idx(tx0 - 1 + i % HS, H);
        float val;
        if (c == 0)      val = -1.f + 2.f * w / (H - 1);
        else if (c == 1) val = -1.f + 2.f * h / (H - 1);
        else if (c < 2 + NF) val = feat[((size_t)(b * NF + c - 2) * H + h) * H + w];
        else {
            int o = c - 2 - NF;
            const float* pb = prev + (size_t)(b * Cp + o) * Hp * Hp;
            float raw = bilin(pb, Hp, (h + 0.5f) * SC - 0.5f, (w + 0.5f) * SC - 0.5f);
            val = raw * pss[2 * o] + pss[2 * o + 1];
        }
        sh[i] = val;
    }
    __syncthreads();

    float s1 = 0.f, s2 = 0.f;
    float* ob = out + (((size_t)(b * C + c)) * H + ty0) * H + tx0;
    float wreg[9];
    if constexpr (TILE == P) {
        const float* wb = wsig + ((size_t)(b * WC + c * 9)) * 64 + (ty0 / P) * 8 + (tx0 / P);
#pragma unroll
        for (int t = 0; t < 9; ++t) wreg[t] = wb[(size_t)t * 64];
    }
#pragma unroll
    for (int k = 0; k < PXPT; ++k) {
        int px = tid + k * 256;
        int tyy = px / TILE, txx = px % TILE;
        if constexpr (TILE != P) {
            int u = (ty0 + tyy) / P, vv = (tx0 + txx) / P;
            const float* wb = wsig + ((size_t)(b * WC + c * 9)) * 64 + u * 8 + vv;
#pragma unroll
            for (int t = 0; t < 9; ++t) wreg[t] = wb[(size_t)t * 64];
        }
        float acc = 0.f;
#pragma unroll
        for (int t = 0; t < 9; ++t)
            acc += wreg[t] * sh[(tyy + t / 3) * HS + txx + t % 3];
        if constexpr (WRITE) ob[tyy * H + txx] = acc;
        s1 += acc; s2 += acc * acc;
    }
#pragma unroll
    for (int off = 32; off; off >>= 1) {
        s1 += __shfl_xor(s1, off);
        s2 += __shfl_xor(s2, off);
    }
    __shared__ float r1[4], r2[4];
    int wave = tid >> 6;
    if ((tid & 63) == 0) { r1[wave] = s1; r2[wave] = s2; }
    __syncthreads();
    if (tid == 0) {
        int slot = bid & 63;
        atomicAdd(&part[slot * 2 * C + 2 * c],     r1[0] + r1[1] + r1[2] + r1[3]);
        atomicAdd(&part[slot * 2 * C + 2 * c + 1], r2[0] + r2[1] + r2[2] + r2[3]);
    }
}

// ---------------- Reduce 64-slot partials -> per-channel (scale, shift) ----------------
__global__ void red_kernel(const float* __restrict__ part, const float* __restrict__ g,
                           const float* __restrict__ bb, float* __restrict__ ss,
                           int C, float invN) {
    int c = threadIdx.x;
    if (c >= C) return;
    float s1 = 0.f, s2 = 0.f;
    for (int s = 0; s < 64; ++s) {
        s1 += part[s * 2 * C + 2 * c];
        s2 += part[s * 2 * C + 2 * c + 1];
    }
    float m = s1 * invN;
    float var = s2 * invN - m * m;
    float sc = g[c] * rsqrtf(var + EPS);
    ss[2 * c] = sc;
    ss[2 * c + 1] = bb[c] - m * sc;
}

// ---------------- Pointwise 1x1, small levels (patch px <= 64) ----------------
template <int C, int ONC, int H, int PX_T, int OC_T>
__global__ __launch_bounds__(256)
void pw_small_kernel(const float* __restrict__ x, const float* __restrict__ wsig,
                     const float* __restrict__ ss, float* __restrict__ out,
                     float* __restrict__ part, int WC, int ndw) {
    constexpr int P = H / 8;
    constexpr int OC_I = ONC / OC_T;
    __shared__ float lw[ONC * C];
    __shared__ float lx[C * PX_T];
    int tid = threadIdx.x, bid = blockIdx.x;
    int uv = bid & 63, b = bid >> 6;
    int u = uv >> 3, v = uv & 7;

    const size_t wbase = ((size_t)b * WC + ndw) * 64 + uv;
    for (int i = tid; i < ONC * C; i += 256) lw[i] = wsig[wbase + (size_t)i * 64];
    for (int i = tid; i < C * PX_T; i += 256) {
        int c = i / PX_T, pxl = i % PX_T;
        int h = u * P + pxl / P, w = v * P + pxl % P;
        float xv = x[(((size_t)b * C + c) * H + h) * H + w];
        lx[i] = fminf(fmaxf(xv * ss[2 * c] + ss[2 * c + 1], 0.f), 6.f);
    }
    __syncthreads();

    int px_id = tid % PX_T, oc_id = tid / PX_T;
    int h = u * P + px_id / P, w = v * P + px_id % P;
    float acc[OC_I];
#pragma unroll
    for (int oi = 0; oi < OC_I; ++oi) acc[oi] = 0.f;
    for (int c = 0; c < C; ++c) {
        float xv = lx[c * PX_T + px_id];
#pragma unroll
        for (int oi = 0; oi < OC_I; ++oi)
            acc[oi] += lw[(oc_id * OC_I + oi) * C + c] * xv;
    }
    float* ob = out + (((size_t)b * ONC) * H + h) * H + w;
#pragma unroll
    for (int oi = 0; oi < OC_I; ++oi)
        ob[(size_t)(oc_id * OC_I + oi) * H * H] = acc[oi];

    constexpr int GROUP = (PX_T < 64) ? PX_T : 64;
    int lane = tid & 63;
    int slot = bid & 63;
#pragma unroll
    for (int oi = 0; oi < OC_I; ++oi) {
        float s1 = acc[oi], s2 = acc[oi] * acc[oi];
#pragma unroll
        for (int off = GROUP / 2; off; off >>= 1) {
            s1 += __shfl_xor(s1, off);
            s2 += __shfl_xor(s2, off);
        }
        if ((lane & (GROUP - 1)) == 0) {
            int o = oc_id * OC_I + oi;
            atomicAdd(&part[slot * 2 * ONC + 2 * o], s1);
            atomicAdd(&part[slot * 2 * ONC + 2 * o + 1], s2);
        }
    }
}

// ---------------- Level 2 fused: rebuild + dw(recompute) + BN/ReLU6 + pw ----------------
// One block = 16x16 tile inside one patch. Halo for all 37 channels in LDS.
__global__ __launch_bounds__(256)
void fused_dwpw2_kernel(const float* __restrict__ ximg, const float* __restrict__ prev,
                        const float* __restrict__ pss, const float* __restrict__ wsig,
                        const float* __restrict__ dss, float* __restrict__ out,
                        float* __restrict__ part) {
    const int C = 37, ONC = 21, H = 256, Hp = 64, Cp = 32, WC = 1110, NDW = 333;
    const int HS = 18;
    __shared__ float sh[C * HS * HS];   // 47952 B
    __shared__ float ldw[333];
    __shared__ float lw[777];
    __shared__ float sdw[74];

    int tid = threadIdx.x, bid = blockIdx.x;
    int tile = bid & 3;
    int uv = (bid >> 2) & 63;
    int b = bid >> 8;
    int y0 = (uv >> 3) * 32 + (tile >> 1) * 16;
    int x0 = (uv & 7) * 32 + (tile & 1) * 16;

    // stage weights + dw BN
    for (int i = tid; i < 333; i += 256) ldw[i] = wsig[((size_t)b * WC + i) * 64 + uv];
    for (int i = tid; i < 777; i += 256) lw[i]  = wsig[((size_t)b * WC + NDW + i) * 64 + uv];
    for (int i = tid; i < 74; i += 256)  sdw[i] = dss[i];

    // stage built halo for all channels
    for (int i = tid; i < C * HS * HS; i += 256) {
        int c = i / (HS * HS), rem = i % (HS * HS);
        int h = reflect_idx(y0 - 1 + rem / HS, H);
        int w = reflect_idx(x0 - 1 + rem % HS, H);
        float val;
        if (c == 0)      val = -1.f + 2.f * w / (H - 1);
        else if (c == 1) val = -1.f + 2.f * h / (H - 1);
        else if (c < 5)  val = ximg[((size_t)(b * 3 + c - 2) * H + h) * H + w];
        else {
            int o = c - 5;
            const float* pb = prev + (size_t)(b * Cp + o) * Hp * Hp;
            float raw = bilin(pb, Hp, (h + 0.5f) * 0.25f - 0.5f, (w + 0.5f) * 0.25f - 0.5f);
            val = raw * pss[2 * o] + pss[2 * o + 1];
        }
        sh[i] = val;
    }
    __syncthreads();

    int tyy = tid >> 4, txx = tid & 15;
    float acc[21];
#pragma unroll
    for (int o = 0; o < 21; ++o) acc[o] = 0.f;

    for (int c = 0; c < C; ++c) {
        const float* sc = sh + c * (HS * HS) + tyy * HS + txx;
        float dwv = 0.f;
#pragma unroll
        for (int t = 0; t < 9; ++t)
            dwv += ldw[c * 9 + t] * sc[(t / 3) * HS + t % 3];
        float xv = fminf(fmaxf(dwv * sdw[2 * c] + sdw[2 * c + 1], 0.f), 6.f);
#pragma unroll
        for (int o = 0; o < 21; ++o)
            acc[o] += lw[o * C + c] * xv;
    }

    float* ob = out + (((size_t)b * ONC) * H + y0 + tyy) * H + x0 + txx;
#pragma unroll
    for (int o = 0; o < 21; ++o) ob[(size_t)o * H * H] = acc[o];

    // striped stats
    __shared__ float r1[4][21], r2[4][21];
    int wave = tid >> 6, lane = tid & 63;
#pragma unroll
    for (int o = 0; o < 21; ++o) {
        float s1 = acc[o], s2 = acc[o] * acc[o];
#pragma unroll
        for (int off = 32; off; off >>= 1) {
            s1 += __shfl_xor(s1, off);
            s2 += __shfl_xor(s2, off);
        }
        if (lane == 0) { r1[wave][o] = s1; r2[wave][o] = s2; }
    }
    __syncthreads();
    int slot = bid & 63;
    for (int o = tid; o < 21; o += 256) {
        atomicAdd(&part[slot * 42 + 2 * o],     r1[0][o] + r1[1][o] + r1[2][o] + r1[3][o]);
        atomicAdd(&part[slot * 42 + 2 * o + 1], r2[0][o] + r2[1][o] + r2[2][o] + r2[3][o]);
    }
}

// ---------------- Final in-place BN (float4) ----------------
__global__ void finalbn_kernel(float* __restrict__ out, const float* __restrict__ ss) {
    int idx = blockIdx.x * 256 + threadIdx.x;
    const int total4 = 4 * 21 * 256 * 256 / 4;
    if (idx >= total4) return;
    int c = (idx / (256 * 256 / 4)) % 21;
    float4 v = ((float4*)out)[idx];
    float sc = ss[2 * c], sb = ss[2 * c + 1];
    v.x = v.x * sc + sb; v.y = v.y * sc + sb; v.z = v.z * sc + sb; v.w = v.w * sc + sb;
    ((float4*)out)[idx] = v;
}

extern "C" void kernel_launch(void* const* d_in, const int* in_sizes, int n_in,
                              void* d_out, int out_size, void* d_ws, size_t ws_size,
                              hipStream_t stream) {
    const float* x_img = (const float*)d_in[0];
    const float* f0    = (const float*)d_in[1];
    const float* f1    = (const float*)d_in[2];
    const float* w0    = (const float*)d_in[3];
    const float* w1    = (const float*)d_in[4];
    const float* w2    = (const float*)d_in[5];
    const float* g_dw0 = (const float*)d_in[6],  *b_dw0 = (const float*)d_in[7];
    const float* g_pw0 = (const float*)d_in[8],  *b_pw0 = (const float*)d_in[9];
    const float* g_dw1 = (const float*)d_in[10], *b_dw1 = (const float*)d_in[11];
    const float* g_pw1 = (const float*)d_in[12], *b_pw1 = (const float*)d_in[13];
    const float* g_dw2 = (const float*)d_in[14], *b_dw2 = (const float*)d_in[15];
    const float* g_pw2 = (const float*)d_in[16], *b_pw2 = (const float*)d_in[17];
    float* out = (float*)d_out;
    float* ws = (float*)d_ws;

    // workspace layout (floats)
    float* part_dw0 = ws;              // 64*132 = 8448
    float* part_pw0 = ws + 8448;       // 64*128 = 8192
    float* part_dw1 = ws + 16640;      // 64*196 = 12544
    float* part_pw1 = ws + 29184;      // 64*64  = 4096
    float* part_dw2 = ws + 33280;      // 64*74  = 4736
    float* part_pw2 = ws + 38016;      // 64*42  = 2688  -> parts end 40704
    float* dw0ss = ws + 40704;         // 132
    float* pw0ss = ws + 40836;         // 128
    float* dw1ss = ws + 40964;         // 196
    float* pw1ss = ws + 41160;         // 64
    float* dw2ss = ws + 41224;         // 74
    float* pw2ss = ws + 41298;         // 42 -> 41340
    float* pw0raw = ws + 41344;        // 4*64*32*32 = 262144
    float* pw1raw = pw0raw + 262144;   // 4*32*64*64 = 524288
    float* bigA   = pw1raw + 524288;   // dw raw for levels 0/1 (<= 4*98*64*64)

    hipMemsetAsync(ws, 0, 40704 * sizeof(float), stream);

    // ---- Level 0: C=66, 32x32, out 64 ----
    fused_dw_kernel<0, true><<<4 * 66 * 4, 256, 0, stream>>>(f1, nullptr, nullptr, w0, bigA, part_dw0);
    red_kernel<<<1, 128, 0, stream>>>(part_dw0, g_dw0, b_dw0, dw0ss, 66, 1.f / 4096.f);
    pw_small_kernel<66, 64, 32, 16, 16><<<256, 256, 0, stream>>>(
        bigA, w0, dw0ss, pw0raw, part_pw0, 4818, 594);
    red_kernel<<<1, 128, 0, stream>>>(part_pw0, g_pw0, b_pw0, pw0ss, 64, 1.f / 4096.f);
    // ---- Level 1: C=98, 64x64, out 32 ----
    fused_dw_kernel<1, true><<<4 * 98 * 16, 256, 0, stream>>>(f0, pw0raw, pw0ss, w1, bigA, part_dw1);
    red_kernel<<<1, 128, 0, stream>>>(part_dw1, g_dw1, b_dw1, dw1ss, 98, 1.f / 16384.f);
    pw_small_kernel<98, 32, 64, 64, 4><<<256, 256, 0, stream>>>(
        bigA, w1, dw1ss, pw1raw, part_pw1, 4018, 882);
    red_kernel<<<1, 128, 0, stream>>>(part_pw1, g_pw1, b_pw1, pw1ss, 32, 1.f / 16384.f);
    // ---- Level 2: C=37, 256x256, out 21 (no dw materialization) ----
    fused_dw_kernel<2, false><<<4 * 37 * 64, 256, 0, stream>>>(x_img, pw1raw, pw1ss, w2, nullptr, part_dw2);
    red_kernel<<<1, 128, 0, stream>>>(part_dw2, g_dw2, b_dw2, dw2ss, 37, 1.f / 262144.f);
    fused_dwpw2_kernel<<<1024, 256, 0, stream>>>(x_img, pw1raw, pw1ss, w2, dw2ss, out, part_pw2);
    red_kernel<<<1, 128, 0, stream>>>(part_pw2, g_pw2, b_pw2, pw2ss, 21, 1.f / 262144.f);
    finalbn_kernel<<<5376, 256, 0, stream>>>(out, pw2ss);
}

// Round 5
// 154.367 us; speedup vs baseline: 1.3077x; 1.3077x over previous
//
#include <hip/hip_runtime.h>

#define EPS 1e-5f

__device__ __forceinline__ int reflect_idx(int i, int n) {
    if (i < 0) return -i;
    if (i >= n) return 2 * n - 2 - i;
    return i;
}

__device__ __forceinline__ float bilin(const float* __restrict__ pb, int Hp, float sy, float sx) {
    int y0 = (int)floorf(sy), x0 = (int)floorf(sx);
    float fy = sy - y0, fx = sx - x0;
    int y0c = min(max(y0, 0), Hp - 1), y1c = min(max(y0 + 1, 0), Hp - 1);
    int x0c = min(max(x0, 0), Hp - 1), x1c = min(max(x0 + 1, 0), Hp - 1);
    float v00 = pb[y0c * Hp + x0c], v01 = pb[y0c * Hp + x1c];
    float v10 = pb[y1c * Hp + x0c], v11 = pb[y1c * Hp + x1c];
    return v00 * (1 - fy) * (1 - fx) + v01 * (1 - fy) * fx
         + v10 * fy * (1 - fx) + v11 * fy * fx;
}

// Per-block redundant reduction of 64-slot striped partials -> (scale, shift) in LDS.
// Deterministic and identical across blocks (same order). Runs on threads < C while
// other threads stage weights concurrently; caller must __syncthreads() after.
__device__ __forceinline__ void reduce_ss_lds(const float* __restrict__ part,
                                              const float* __restrict__ g,
                                              const float* __restrict__ bb,
                                              float* ss, int C, float invN, int tid) {
    for (int c = tid; c < C; c += 256) {
        float s1 = 0.f, s2 = 0.f;
#pragma unroll 8
        for (int s = 0; s < 64; ++s) {
            s1 += part[s * 2 * C + 2 * c];
            s2 += part[s * 2 * C + 2 * c + 1];
        }
        float m = s1 * invN;
        float var = s2 * invN - m * m;
        float sc = g[c] * rsqrtf(var + EPS);
        ss[2 * c] = sc;
        ss[2 * c + 1] = bb[c] - m * sc;
    }
}

// ---------------- Fused build + depthwise 3x3 + striped stats ----------------
// Merged preamble: reduces previous-pw partials into BN (scale,shift) in LDS.
template <int LEVEL, bool WRITE>
__global__ __launch_bounds__(256)
void fused_dw_kernel(const float* __restrict__ feat, const float* __restrict__ prev,
                     const float* __restrict__ part_prev, const float* __restrict__ g_prev,
                     const float* __restrict__ b_prev, float invN_prev,
                     const float* __restrict__ wsig,
                     float* __restrict__ out, float* __restrict__ part) {
    constexpr int C    = LEVEL == 0 ? 66 : LEVEL == 1 ? 98 : 37;
    constexpr int H    = LEVEL == 0 ? 32 : LEVEL == 1 ? 64 : 256;
    constexpr int TILE = LEVEL == 2 ? 32 : 16;
    constexpr int NT   = H / TILE;
    constexpr int PXPT = (TILE * TILE) / 256;
    constexpr int WC   = LEVEL == 0 ? 4818 : LEVEL == 1 ? 4018 : 1110;
    constexpr int NF   = LEVEL == 0 ? 64 : LEVEL == 1 ? 32 : 3;
    constexpr int Hp   = LEVEL == 1 ? 32 : 64;
    constexpr int Cp   = LEVEL == 1 ? 64 : 32;
    constexpr int P    = H / 8;
    constexpr float SC = LEVEL == 1 ? 0.5f : 0.25f;
    constexpr int HS   = TILE + 2;
    constexpr int PSS  = (LEVEL == 0) ? 2 : 2 * Cp;

    __shared__ float sh[HS * HS];
    __shared__ float pssl[PSS];
    int tid = threadIdx.x, bid = blockIdx.x;
    int tile = bid % (NT * NT);
    int c = (bid / (NT * NT)) % C;
    int b = bid / (NT * NT * C);
    int ty0 = (tile / NT) * TILE, tx0 = (tile % NT) * TILE;

    if constexpr (LEVEL != 0) {
        reduce_ss_lds(part_prev, g_prev, b_prev, pssl, Cp, invN_prev, tid);
        __syncthreads();
    }

    for (int i = tid; i < HS * HS; i += 256) {
        int h = reflect_idx(ty0 - 1 + i / HS, H);
        int w = reflect_idx(tx0 - 1 + i % HS, H);
        float val;
        if (c == 0)      val = -1.f + 2.f * w / (H - 1);
        else if (c == 1) val = -1.f + 2.f * h / (H - 1);
        else if (c < 2 + NF) val = feat[((size_t)(b * NF + c - 2) * H + h) * H + w];
        else {
            int o = c - 2 - NF;
            const float* pb = prev + (size_t)(b * Cp + o) * Hp * Hp;
            float raw = bilin(pb, Hp, (h + 0.5f) * SC - 0.5f, (w + 0.5f) * SC - 0.5f);
            val = raw * pssl[2 * o] + pssl[2 * o + 1];
        }
        sh[i] = val;
    }
    __syncthreads();

    float s1 = 0.f, s2 = 0.f;
    float* ob = out + (((size_t)(b * C + c)) * H + ty0) * H + tx0;
    float wreg[9];
    if constexpr (TILE == P) {
        const float* wb = wsig + ((size_t)(b * WC + c * 9)) * 64 + (ty0 / P) * 8 + (tx0 / P);
#pragma unroll
        for (int t = 0; t < 9; ++t) wreg[t] = wb[(size_t)t * 64];
    }
#pragma unroll
    for (int k = 0; k < PXPT; ++k) {
        int px = tid + k * 256;
        int tyy = px / TILE, txx = px % TILE;
        if constexpr (TILE != P) {
            int u = (ty0 + tyy) / P, vv = (tx0 + txx) / P;
            const float* wb = wsig + ((size_t)(b * WC + c * 9)) * 64 + u * 8 + vv;
#pragma unroll
            for (int t = 0; t < 9; ++t) wreg[t] = wb[(size_t)t * 64];
        }
        float acc = 0.f;
#pragma unroll
        for (int t = 0; t < 9; ++t)
            acc += wreg[t] * sh[(tyy + t / 3) * HS + txx + t % 3];
        if constexpr (WRITE) ob[tyy * H + txx] = acc;
        s1 += acc; s2 += acc * acc;
    }
#pragma unroll
    for (int off = 32; off; off >>= 1) {
        s1 += __shfl_xor(s1, off);
        s2 += __shfl_xor(s2, off);
    }
    __shared__ float r1[4], r2[4];
    int wave = tid >> 6;
    if ((tid & 63) == 0) { r1[wave] = s1; r2[wave] = s2; }
    __syncthreads();
    if (tid == 0) {
        int slot = bid & 63;
        atomicAdd(&part[slot * 2 * C + 2 * c],     r1[0] + r1[1] + r1[2] + r1[3]);
        atomicAdd(&part[slot * 2 * C + 2 * c + 1], r2[0] + r2[1] + r2[2] + r2[3]);
    }
}

// ---------------- Pointwise 1x1, small levels, merged dw-stats reduce ----------------
template <int C, int ONC, int H, int PX_T, int OC_T>
__global__ __launch_bounds__(256)
void pw_small_kernel(const float* __restrict__ x, const float* __restrict__ wsig,
                     const float* __restrict__ part_in, const float* __restrict__ g,
                     const float* __restrict__ bb, float invN,
                     float* __restrict__ out, float* __restrict__ part, int WC, int ndw) {
    constexpr int P = H / 8;
    constexpr int OC_I = ONC / OC_T;
    __shared__ float lw[ONC * C];
    __shared__ float lx[C * PX_T];
    __shared__ float ssl[2 * C];
    int tid = threadIdx.x, bid = blockIdx.x;
    int uv = bid & 63, b = bid >> 6;
    int u = uv >> 3, v = uv & 7;

    const size_t wbase = ((size_t)b * WC + ndw) * 64 + uv;
    for (int i = tid; i < ONC * C; i += 256) lw[i] = wsig[wbase + (size_t)i * 64];
    reduce_ss_lds(part_in, g, bb, ssl, C, invN, tid);
    __syncthreads();

    for (int i = tid; i < C * PX_T; i += 256) {
        int c = i / PX_T, pxl = i % PX_T;
        int h = u * P + pxl / P, w = v * P + pxl % P;
        float xv = x[(((size_t)b * C + c) * H + h) * H + w];
        lx[i] = fminf(fmaxf(xv * ssl[2 * c] + ssl[2 * c + 1], 0.f), 6.f);
    }
    __syncthreads();

    int px_id = tid % PX_T, oc_id = tid / PX_T;
    int h = u * P + px_id / P, w = v * P + px_id % P;
    float acc[OC_I];
#pragma unroll
    for (int oi = 0; oi < OC_I; ++oi) acc[oi] = 0.f;
    for (int c = 0; c < C; ++c) {
        float xv = lx[c * PX_T + px_id];
#pragma unroll
        for (int oi = 0; oi < OC_I; ++oi)
            acc[oi] += lw[(oc_id * OC_I + oi) * C + c] * xv;
    }
    float* ob = out + (((size_t)b * ONC) * H + h) * H + w;
#pragma unroll
    for (int oi = 0; oi < OC_I; ++oi)
        ob[(size_t)(oc_id * OC_I + oi) * H * H] = acc[oi];

    constexpr int GROUP = (PX_T < 64) ? PX_T : 64;
    int lane = tid & 63;
    int slot = bid & 63;
#pragma unroll
    for (int oi = 0; oi < OC_I; ++oi) {
        float s1 = acc[oi], s2 = acc[oi] * acc[oi];
#pragma unroll
        for (int off = GROUP / 2; off; off >>= 1) {
            s1 += __shfl_xor(s1, off);
            s2 += __shfl_xor(s2, off);
        }
        if ((lane & (GROUP - 1)) == 0) {
            int o = oc_id * OC_I + oi;
            atomicAdd(&part[slot * 2 * ONC + 2 * o], s1);
            atomicAdd(&part[slot * 2 * ONC + 2 * o + 1], s2);
        }
    }
}

// ---------------- Pointwise 1x1 level 2: float4, merged dw2-stats reduce ----------------
__global__ __launch_bounds__(256)
void pw2_kernel(const float* __restrict__ x, const float* __restrict__ wsig,
                const float* __restrict__ part_in, const float* __restrict__ g,
                const float* __restrict__ bb,
                float* __restrict__ out, float* __restrict__ part) {
    const int C = 37, ONC = 21, H = 256, PATCH = 32, WC = 1110, NDW = 333;
    __shared__ float lw[ONC * C];
    __shared__ float ssl[2 * C];
    __shared__ float r1[4][ONC], r2[4][ONC];
    int tid = threadIdx.x, bid = blockIdx.x;
    int uv = bid & 63, b = bid >> 6;
    int y0 = (uv >> 3) * PATCH, x0 = (uv & 7) * PATCH;

    for (int i = tid; i < ONC * C; i += 256) lw[i] = wsig[((size_t)(b * WC + NDW) + i) * 64 + uv];
    reduce_ss_lds(part_in, g, bb, ssl, C, 1.f / 262144.f, tid);
    __syncthreads();

    int row = tid >> 3, col = (tid & 7) * 4;
    const float* xb = x + (((size_t)b * C) * H + y0 + row) * H + x0 + col;
    float4 acc[ONC];
#pragma unroll
    for (int o = 0; o < ONC; ++o) acc[o] = make_float4(0.f, 0.f, 0.f, 0.f);

    for (int c = 0; c < C; ++c) {
        float4 xv = *(const float4*)(xb + (size_t)c * H * H);
        float sc = ssl[2 * c], sb = ssl[2 * c + 1];
        xv.x = fminf(fmaxf(xv.x * sc + sb, 0.f), 6.f);
        xv.y = fminf(fmaxf(xv.y * sc + sb, 0.f), 6.f);
        xv.z = fminf(fmaxf(xv.z * sc + sb, 0.f), 6.f);
        xv.w = fminf(fmaxf(xv.w * sc + sb, 0.f), 6.f);
#pragma unroll
        for (int o = 0; o < ONC; ++o) {
            float wv = lw[o * C + c];
            acc[o].x += wv * xv.x;
            acc[o].y += wv * xv.y;
            acc[o].z += wv * xv.z;
            acc[o].w += wv * xv.w;
        }
    }
    float* ob = out + (((size_t)b * ONC) * H + y0 + row) * H + x0 + col;
#pragma unroll
    for (int o = 0; o < ONC; ++o) *(float4*)(ob + (size_t)o * H * H) = acc[o];

    int wave = tid >> 6, lane = tid & 63;
#pragma unroll
    for (int o = 0; o < ONC; ++o) {
        float s1 = acc[o].x + acc[o].y + acc[o].z + acc[o].w;
        float s2 = acc[o].x * acc[o].x + acc[o].y * acc[o].y
                 + acc[o].z * acc[o].z + acc[o].w * acc[o].w;
#pragma unroll
        for (int off = 32; off; off >>= 1) {
            s1 += __shfl_xor(s1, off);
            s2 += __shfl_xor(s2, off);
        }
        if (lane == 0) { r1[wave][o] = s1; r2[wave][o] = s2; }
    }
    __syncthreads();
    int slot = bid & 63;
    for (int o = tid; o < ONC; o += 256) {
        atomicAdd(&part[slot * 42 + 2 * o],     r1[0][o] + r1[1][o] + r1[2][o] + r1[3][o]);
        atomicAdd(&part[slot * 42 + 2 * o + 1], r2[0][o] + r2[1][o] + r2[2][o] + r2[3][o]);
    }
}

// ---------------- Final in-place BN (float4, grid-stride, merged pw2-stats reduce) ----------------
__global__ __launch_bounds__(256)
void finalbn_kernel(float* __restrict__ out, const float* __restrict__ part_in,
                    const float* __restrict__ g, const float* __restrict__ bb) {
    __shared__ float ssl[42];
    reduce_ss_lds(part_in, g, bb, ssl, 21, 1.f / 262144.f, threadIdx.x);
    __syncthreads();
    const int total4 = 4 * 21 * 256 * 256 / 4;
    for (int idx = blockIdx.x * 256 + threadIdx.x; idx < total4; idx += gridDim.x * 256) {
        int c = (idx / (256 * 256 / 4)) % 21;
        float4 v = ((float4*)out)[idx];
        float sc = ssl[2 * c], sb = ssl[2 * c + 1];
        v.x = v.x * sc + sb; v.y = v.y * sc + sb; v.z = v.z * sc + sb; v.w = v.w * sc + sb;
        ((float4*)out)[idx] = v;
    }
}

extern "C" void kernel_launch(void* const* d_in, const int* in_sizes, int n_in,
                              void* d_out, int out_size, void* d_ws, size_t ws_size,
                              hipStream_t stream) {
    const float* x_img = (const float*)d_in[0];
    const float* f0    = (const float*)d_in[1];
    const float* f1    = (const float*)d_in[2];
    const float* w0    = (const float*)d_in[3];
    const float* w1    = (const float*)d_in[4];
    const float* w2    = (const float*)d_in[5];
    const float* g_dw0 = (const float*)d_in[6],  *b_dw0 = (const float*)d_in[7];
    const float* g_pw0 = (const float*)d_in[8],  *b_pw0 = (const float*)d_in[9];
    const float* g_dw1 = (const float*)d_in[10], *b_dw1 = (const float*)d_in[11];
    const float* g_pw1 = (const float*)d_in[12], *b_pw1 = (const float*)d_in[13];
    const float* g_dw2 = (const float*)d_in[14], *b_dw2 = (const float*)d_in[15];
    const float* g_pw2 = (const float*)d_in[16], *b_pw2 = (const float*)d_in[17];
    float* out = (float*)d_out;
    float* ws = (float*)d_ws;

    // workspace layout (floats)
    float* part_dw0 = ws;              // 64*132 = 8448
    float* part_pw0 = ws + 8448;       // 64*128 = 8192
    float* part_dw1 = ws + 16640;      // 64*196 = 12544
    float* part_pw1 = ws + 29184;      // 64*64  = 4096
    float* part_dw2 = ws + 33280;      // 64*74  = 4736
    float* part_pw2 = ws + 38016;      // 64*42  = 2688  -> parts end 40704
    float* pw0raw = ws + 40704;        // 4*64*32*32 = 262144
    float* pw1raw = pw0raw + 262144;   // 4*32*64*64 = 524288
    float* bigA   = pw1raw + 524288;   // dw raw, up to 4*37*256*256 = 9699328

    hipMemsetAsync(ws, 0, 40704 * sizeof(float), stream);

    // ---- Level 0: C=66, 32x32, out 64 ----
    fused_dw_kernel<0, true><<<4 * 66 * 4, 256, 0, stream>>>(
        f1, nullptr, nullptr, nullptr, nullptr, 0.f, w0, bigA, part_dw0);
    pw_small_kernel<66, 64, 32, 16, 16><<<256, 256, 0, stream>>>(
        bigA, w0, part_dw0, g_dw0, b_dw0, 1.f / 4096.f, pw0raw, part_pw0, 4818, 594);
    // ---- Level 1: C=98, 64x64, out 32 ----
    fused_dw_kernel<1, true><<<4 * 98 * 16, 256, 0, stream>>>(
        f0, pw0raw, part_pw0, g_pw0, b_pw0, 1.f / 4096.f, w1, bigA, part_dw1);
    pw_small_kernel<98, 32, 64, 64, 4><<<256, 256, 0, stream>>>(
        bigA, w1, part_dw1, g_dw1, b_dw1, 1.f / 16384.f, pw1raw, part_pw1, 4018, 882);
    // ---- Level 2: C=37, 256x256, out 21 ----
    fused_dw_kernel<2, true><<<4 * 37 * 64, 256, 0, stream>>>(
        x_img, pw1raw, part_pw1, g_pw1, b_pw1, 1.f / 16384.f, w2, bigA, part_dw2);
    pw2_kernel<<<256, 256, 0, stream>>>(bigA, w2, part_dw2, g_dw2, b_dw2, out, part_pw2);
    finalbn_kernel<<<1024, 256, 0, stream>>>(out, part_pw2, g_pw2, b_pw2);
}

// Round 6
// 151.722 us; speedup vs baseline: 1.3305x; 1.0174x over previous
//
#include <hip/hip_runtime.h>

#define EPS 1e-5f

__device__ __forceinline__ int reflect_idx(int i, int n) {
    if (i < 0) return -i;
    if (i >= n) return 2 * n - 2 - i;
    return i;
}

__device__ __forceinline__ float bilin(const float* __restrict__ pb, int Hp, float sy, float sx) {
    int y0 = (int)floorf(sy), x0 = (int)floorf(sx);
    float fy = sy - y0, fx = sx - x0;
    int y0c = min(max(y0, 0), Hp - 1), y1c = min(max(y0 + 1, 0), Hp - 1);
    int x0c = min(max(x0, 0), Hp - 1), x1c = min(max(x0 + 1, 0), Hp - 1);
    float v00 = pb[y0c * Hp + x0c], v01 = pb[y0c * Hp + x1c];
    float v10 = pb[y1c * Hp + x0c], v11 = pb[y1c * Hp + x1c];
    return v00 * (1 - fy) * (1 - fx) + v01 * (1 - fy) * fx
         + v10 * fy * (1 - fx) + v11 * fy * fx;
}

// Per-block redundant reduction of 64-slot striped partials -> (scale, shift) in LDS.
__device__ __forceinline__ void reduce_ss_lds(const float* __restrict__ part,
                                              const float* __restrict__ g,
                                              const float* __restrict__ bb,
                                              float* ss, int C, float invN, int tid) {
    for (int c = tid; c < C; c += 256) {
        float s1 = 0.f, s2 = 0.f;
#pragma unroll 8
        for (int s = 0; s < 64; ++s) {
            s1 += part[s * 2 * C + 2 * c];
            s2 += part[s * 2 * C + 2 * c + 1];
        }
        float m = s1 * invN;
        float var = s2 * invN - m * m;
        float sc = g[c] * rsqrtf(var + EPS);
        ss[2 * c] = sc;
        ss[2 * c + 1] = bb[c] - m * sc;
    }
}

// ---------------- Fused build + depthwise 3x3 + striped stats (levels 0/1) ----------------
template <int LEVEL, bool WRITE>
__global__ __launch_bounds__(256)
void fused_dw_kernel(const float* __restrict__ feat, const float* __restrict__ prev,
                     const float* __restrict__ part_prev, const float* __restrict__ g_prev,
                     const float* __restrict__ b_prev, float invN_prev,
                     const float* __restrict__ wsig,
                     float* __restrict__ out, float* __restrict__ part) {
    constexpr int C    = LEVEL == 0 ? 66 : LEVEL == 1 ? 98 : 37;
    constexpr int H    = LEVEL == 0 ? 32 : LEVEL == 1 ? 64 : 256;
    constexpr int TILE = LEVEL == 2 ? 32 : 16;
    constexpr int NT   = H / TILE;
    constexpr int PXPT = (TILE * TILE) / 256;
    constexpr int WC   = LEVEL == 0 ? 4818 : LEVEL == 1 ? 4018 : 1110;
    constexpr int NF   = LEVEL == 0 ? 64 : LEVEL == 1 ? 32 : 3;
    constexpr int Hp   = LEVEL == 1 ? 32 : 64;
    constexpr int Cp   = LEVEL == 1 ? 64 : 32;
    constexpr int P    = H / 8;
    constexpr float SC = LEVEL == 1 ? 0.5f : 0.25f;
    constexpr int HS   = TILE + 2;
    constexpr int PSS  = (LEVEL == 0) ? 2 : 2 * Cp;

    __shared__ float sh[HS * HS];
    __shared__ float pssl[PSS];
    int tid = threadIdx.x, bid = blockIdx.x;
    int tile = bid % (NT * NT);
    int c = (bid / (NT * NT)) % C;
    int b = bid / (NT * NT * C);
    int ty0 = (tile / NT) * TILE, tx0 = (tile % NT) * TILE;

    if constexpr (LEVEL != 0) {
        reduce_ss_lds(part_prev, g_prev, b_prev, pssl, Cp, invN_prev, tid);
        __syncthreads();
    }

    for (int i = tid; i < HS * HS; i += 256) {
        int h = reflect_idx(ty0 - 1 + i / HS, H);
        int w = reflect_idx(tx0 - 1 + i % HS, H);
        float val;
        if (c == 0)      val = -1.f + 2.f * w / (H - 1);
        else if (c == 1) val = -1.f + 2.f * h / (H - 1);
        else if (c < 2 + NF) val = feat[((size_t)(b * NF + c - 2) * H + h) * H + w];
        else {
            int o = c - 2 - NF;
            const float* pb = prev + (size_t)(b * Cp + o) * Hp * Hp;
            float raw = bilin(pb, Hp, (h + 0.5f) * SC - 0.5f, (w + 0.5f) * SC - 0.5f);
            val = raw * pssl[2 * o] + pssl[2 * o + 1];
        }
        sh[i] = val;
    }
    __syncthreads();

    float s1 = 0.f, s2 = 0.f;
    float* ob = out + (((size_t)(b * C + c)) * H + ty0) * H + tx0;
    float wreg[9];
    if constexpr (TILE == P) {
        const float* wb = wsig + ((size_t)(b * WC + c * 9)) * 64 + (ty0 / P) * 8 + (tx0 / P);
#pragma unroll
        for (int t = 0; t < 9; ++t) wreg[t] = wb[(size_t)t * 64];
    }
#pragma unroll
    for (int k = 0; k < PXPT; ++k) {
        int px = tid + k * 256;
        int tyy = px / TILE, txx = px % TILE;
        if constexpr (TILE != P) {
            int u = (ty0 + tyy) / P, vv = (tx0 + txx) / P;
            const float* wb = wsig + ((size_t)(b * WC + c * 9)) * 64 + u * 8 + vv;
#pragma unroll
            for (int t = 0; t < 9; ++t) wreg[t] = wb[(size_t)t * 64];
        }
        float acc = 0.f;
#pragma unroll
        for (int t = 0; t < 9; ++t)
            acc += wreg[t] * sh[(tyy + t / 3) * HS + txx + t % 3];
        if constexpr (WRITE) ob[tyy * H + txx] = acc;
        s1 += acc; s2 += acc * acc;
    }
#pragma unroll
    for (int off = 32; off; off >>= 1) {
        s1 += __shfl_xor(s1, off);
        s2 += __shfl_xor(s2, off);
    }
    __shared__ float r1[4], r2[4];
    int wave = tid >> 6;
    if ((tid & 63) == 0) { r1[wave] = s1; r2[wave] = s2; }
    __syncthreads();
    if (tid == 0) {
        int slot = bid & 63;
        atomicAdd(&part[slot * 2 * C + 2 * c],     r1[0] + r1[1] + r1[2] + r1[3]);
        atomicAdd(&part[slot * 2 * C + 2 * c + 1], r2[0] + r2[1] + r2[2] + r2[3]);
    }
}

// ---------------- Level-2 dw: row-streaming. Block = (b, c, 8 rows) ----------------
__global__ __launch_bounds__(256)
void dw2_row_kernel(const float* __restrict__ ximg, const float* __restrict__ prev,
                    const float* __restrict__ part_prev, const float* __restrict__ g_prev,
                    const float* __restrict__ b_prev,
                    const float* __restrict__ wsig,
                    float* __restrict__ out, float* __restrict__ part) {
    const int C = 37, H = 256, W = 256, WC = 1110, Hp = 64, Cp = 32;
    const int S = 260;                    // LDS row stride (floats)
    __shared__ float sh[10 * S];          // 10.4 KB halo (rows ty0-1..ty0+8, cols -1..256)
    __shared__ float pssl[64];
    __shared__ float lwv[72];
    __shared__ float r1[4], r2[4];

    int tid = threadIdx.x, bid = blockIdx.x;
    int rb = bid & 31;
    int c  = (bid >> 5) % C;
    int b  = bid / (32 * C);
    int ty0 = rb * 8;
    int u = ty0 >> 5;

    reduce_ss_lds(part_prev, g_prev, b_prev, pssl, Cp, 1.f / 16384.f, tid);
    if (tid < 72) {
        int v = tid / 9, t = tid % 9;
        lwv[tid] = wsig[((size_t)(b * WC + c * 9 + t)) * 64 + u * 8 + v];
    }
    __syncthreads();

    // stage built halo for this channel
    for (int i = tid; i < 10 * 258; i += 256) {
        int r = i / 258, wcol = i % 258 - 1;
        int h = reflect_idx(ty0 - 1 + r, H);
        int w = reflect_idx(wcol, W);
        float val;
        if (c == 0)      val = -1.f + 2.f * w / 255.f;
        else if (c == 1) val = -1.f + 2.f * h / 255.f;
        else if (c < 5)  val = ximg[((size_t)(b * 3 + c - 2) * H + h) * W + w];
        else {
            int o = c - 5;
            const float* pb = prev + (size_t)(b * Cp + o) * Hp * Hp;
            float raw = bilin(pb, Hp, (h + 0.5f) * 0.25f - 0.5f, (w + 0.5f) * 0.25f - 0.5f);
            val = raw * pssl[2 * o] + pssl[2 * o + 1];
        }
        sh[r * S + wcol + 1] = val;
    }
    __syncthreads();

    int row = tid >> 5;                // 0..7
    int col0 = (tid & 31) * 8;         // 0..248
    int v = col0 >> 5;
    float wr[9];
#pragma unroll
    for (int t = 0; t < 9; ++t) wr[t] = lwv[v * 9 + t];

    float px[8];
#pragma unroll
    for (int k = 0; k < 8; ++k) px[k] = 0.f;

#pragma unroll
    for (int dr = 0; dr < 3; ++dr) {
        const float* base = &sh[(row + dr) * S + col0];
        float t0[10];
        float4 q0 = *(const float4*)(base);
        float4 q1 = *(const float4*)(base + 4);
        t0[0] = q0.x; t0[1] = q0.y; t0[2] = q0.z; t0[3] = q0.w;
        t0[4] = q1.x; t0[5] = q1.y; t0[6] = q1.z; t0[7] = q1.w;
        t0[8] = base[8]; t0[9] = base[9];
        float w0 = wr[dr * 3], w1 = wr[dr * 3 + 1], w2 = wr[dr * 3 + 2];
#pragma unroll
        for (int k = 0; k < 8; ++k)
            px[k] += w0 * t0[k] + w1 * t0[k + 1] + w2 * t0[k + 2];
    }

    float* ob = out + (((size_t)(b * C + c)) * H + ty0 + row) * W + col0;
    *(float4*)ob       = make_float4(px[0], px[1], px[2], px[3]);
    *(float4*)(ob + 4) = make_float4(px[4], px[5], px[6], px[7]);

    float s1 = 0.f, s2 = 0.f;
#pragma unroll
    for (int k = 0; k < 8; ++k) { s1 += px[k]; s2 += px[k] * px[k]; }
#pragma unroll
    for (int off = 32; off; off >>= 1) {
        s1 += __shfl_xor(s1, off);
        s2 += __shfl_xor(s2, off);
    }
    int wave = tid >> 6;
    if ((tid & 63) == 0) { r1[wave] = s1; r2[wave] = s2; }
    __syncthreads();
    if (tid == 0) {
        int slot = bid & 63;
        atomicAdd(&part[slot * 2 * C + 2 * c],     r1[0] + r1[1] + r1[2] + r1[3]);
        atomicAdd(&part[slot * 2 * C + 2 * c + 1], r2[0] + r2[1] + r2[2] + r2[3]);
    }
}

// ---------------- Pointwise 1x1, small levels, merged dw-stats reduce ----------------
template <int C, int ONC, int H, int PX_T, int OC_T>
__global__ __launch_bounds__(256)
void pw_small_kernel(const float* __restrict__ x, const float* __restrict__ wsig,
                     const float* __restrict__ part_in, const float* __restrict__ g,
                     const float* __restrict__ bb, float invN,
                     float* __restrict__ out, float* __restrict__ part, int WC, int ndw) {
    constexpr int P = H / 8;
    constexpr int OC_I = ONC / OC_T;
    __shared__ float lw[ONC * C];
    __shared__ float lx[C * PX_T];
    __shared__ float ssl[2 * C];
    int tid = threadIdx.x, bid = blockIdx.x;
    int uv = bid & 63, b = bid >> 6;
    int u = uv >> 3, v = uv & 7;

    const size_t wbase = ((size_t)b * WC + ndw) * 64 + uv;
    for (int i = tid; i < ONC * C; i += 256) lw[i] = wsig[wbase + (size_t)i * 64];
    reduce_ss_lds(part_in, g, bb, ssl, C, invN, tid);
    __syncthreads();

    for (int i = tid; i < C * PX_T; i += 256) {
        int c = i / PX_T, pxl = i % PX_T;
        int h = u * P + pxl / P, w = v * P + pxl % P;
        float xv = x[(((size_t)b * C + c) * H + h) * H + w];
        lx[i] = fminf(fmaxf(xv * ssl[2 * c] + ssl[2 * c + 1], 0.f), 6.f);
    }
    __syncthreads();

    int px_id = tid % PX_T, oc_id = tid / PX_T;
    int h = u * P + px_id / P, w = v * P + px_id % P;
    float acc[OC_I];
#pragma unroll
    for (int oi = 0; oi < OC_I; ++oi) acc[oi] = 0.f;
    for (int c = 0; c < C; ++c) {
        float xv = lx[c * PX_T + px_id];
#pragma unroll
        for (int oi = 0; oi < OC_I; ++oi)
            acc[oi] += lw[(oc_id * OC_I + oi) * C + c] * xv;
    }
    float* ob = out + (((size_t)b * ONC) * H + h) * H + w;
#pragma unroll
    for (int oi = 0; oi < OC_I; ++oi)
        ob[(size_t)(oc_id * OC_I + oi) * H * H] = acc[oi];

    constexpr int GROUP = (PX_T < 64) ? PX_T : 64;
    int lane = tid & 63;
    int slot = bid & 63;
#pragma unroll
    for (int oi = 0; oi < OC_I; ++oi) {
        float s1 = acc[oi], s2 = acc[oi] * acc[oi];
#pragma unroll
        for (int off = GROUP / 2; off; off >>= 1) {
            s1 += __shfl_xor(s1, off);
            s2 += __shfl_xor(s2, off);
        }
        if ((lane & (GROUP - 1)) == 0) {
            int o = oc_id * OC_I + oi;
            atomicAdd(&part[slot * 2 * ONC + 2 * o], s1);
            atomicAdd(&part[slot * 2 * ONC + 2 * o + 1], s2);
        }
    }
}

// ---------------- Pointwise 1x1 level 2: float4, merged dw2-stats reduce ----------------
__global__ __launch_bounds__(256)
void pw2_kernel(const float* __restrict__ x, const float* __restrict__ wsig,
                const float* __restrict__ part_in, const float* __restrict__ g,
                const float* __restrict__ bb,
                float* __restrict__ out, float* __restrict__ part) {
    const int C = 37, ONC = 21, H = 256, PATCH = 32, WC = 1110, NDW = 333;
    __shared__ float lw[ONC * C];
    __shared__ float ssl[2 * C];
    __shared__ float r1[4][ONC], r2[4][ONC];
    int tid = threadIdx.x, bid = blockIdx.x;
    int uv = bid & 63, b = bid >> 6;
    int y0 = (uv >> 3) * PATCH, x0 = (uv & 7) * PATCH;

    for (int i = tid; i < ONC * C; i += 256) lw[i] = wsig[((size_t)(b * WC + NDW) + i) * 64 + uv];
    reduce_ss_lds(part_in, g, bb, ssl, C, 1.f / 262144.f, tid);
    __syncthreads();

    int row = tid >> 3, col = (tid & 7) * 4;
    const float* xb = x + (((size_t)b * C) * H + y0 + row) * H + x0 + col;
    float4 acc[ONC];
#pragma unroll
    for (int o = 0; o < ONC; ++o) acc[o] = make_float4(0.f, 0.f, 0.f, 0.f);

    for (int c = 0; c < C; ++c) {
        float4 xv = *(const float4*)(xb + (size_t)c * H * H);
        float sc = ssl[2 * c], sb = ssl[2 * c + 1];
        xv.x = fminf(fmaxf(xv.x * sc + sb, 0.f), 6.f);
        xv.y = fminf(fmaxf(xv.y * sc + sb, 0.f), 6.f);
        xv.z = fminf(fmaxf(xv.z * sc + sb, 0.f), 6.f);
        xv.w = fminf(fmaxf(xv.w * sc + sb, 0.f), 6.f);
#pragma unroll
        for (int o = 0; o < ONC; ++o) {
            float wv = lw[o * C + c];
            acc[o].x += wv * xv.x;
            acc[o].y += wv * xv.y;
            acc[o].z += wv * xv.z;
            acc[o].w += wv * xv.w;
        }
    }
    float* ob = out + (((size_t)b * ONC) * H + y0 + row) * H + x0 + col;
#pragma unroll
    for (int o = 0; o < ONC; ++o) *(float4*)(ob + (size_t)o * H * H) = acc[o];

    int wave = tid >> 6, lane = tid & 63;
#pragma unroll
    for (int o = 0; o < ONC; ++o) {
        float s1 = acc[o].x + acc[o].y + acc[o].z + acc[o].w;
        float s2 = acc[o].x * acc[o].x + acc[o].y * acc[o].y
                 + acc[o].z * acc[o].z + acc[o].w * acc[o].w;
#pragma unroll
        for (int off = 32; off; off >>= 1) {
            s1 += __shfl_xor(s1, off);
            s2 += __shfl_xor(s2, off);
        }
        if (lane == 0) { r1[wave][o] = s1; r2[wave][o] = s2; }
    }
    __syncthreads();
    int slot = bid & 63;
    for (int o = tid; o < ONC; o += 256) {
        atomicAdd(&part[slot * 42 + 2 * o],     r1[0][o] + r1[1][o] + r1[2][o] + r1[3][o]);
        atomicAdd(&part[slot * 42 + 2 * o + 1], r2[0][o] + r2[1][o] + r2[2][o] + r2[3][o]);
    }
}

// ---------------- Final in-place BN (float4, grid-stride, merged pw2-stats reduce) ----------------
__global__ __launch_bounds__(256)
void finalbn_kernel(float* __restrict__ out, const float* __restrict__ part_in,
                    const float* __restrict__ g, const float* __restrict__ bb) {
    __shared__ float ssl[42];
    reduce_ss_lds(part_in, g, bb, ssl, 21, 1.f / 262144.f, threadIdx.x);
    __syncthreads();
    const int total4 = 4 * 21 * 256 * 256 / 4;
    for (int idx = blockIdx.x * 256 + threadIdx.x; idx < total4; idx += gridDim.x * 256) {
        int c = (idx / (256 * 256 / 4)) % 21;
        float4 v = ((float4*)out)[idx];
        float sc = ssl[2 * c], sb = ssl[2 * c + 1];
        v.x = v.x * sc + sb; v.y = v.y * sc + sb; v.z = v.z * sc + sb; v.w = v.w * sc + sb;
        ((float4*)out)[idx] = v;
    }
}

extern "C" void kernel_launch(void* const* d_in, const int* in_sizes, int n_in,
                              void* d_out, int out_size, void* d_ws, size_t ws_size,
                              hipStream_t stream) {
    const float* x_img = (const float*)d_in[0];
    const float* f0    = (const float*)d_in[1];
    const float* f1    = (const float*)d_in[2];
    const float* w0    = (const float*)d_in[3];
    const float* w1    = (const float*)d_in[4];
    const float* w2    = (const float*)d_in[5];
    const float* g_dw0 = (const float*)d_in[6],  *b_dw0 = (const float*)d_in[7];
    const float* g_pw0 = (const float*)d_in[8],  *b_pw0 = (const float*)d_in[9];
    const float* g_dw1 = (const float*)d_in[10], *b_dw1 = (const float*)d_in[11];
    const float* g_pw1 = (const float*)d_in[12], *b_pw1 = (const float*)d_in[13];
    const float* g_dw2 = (const float*)d_in[14], *b_dw2 = (const float*)d_in[15];
    const float* g_pw2 = (const float*)d_in[16], *b_pw2 = (const float*)d_in[17];
    float* out = (float*)d_out;
    float* ws = (float*)d_ws;

    // workspace layout (floats)
    float* part_dw0 = ws;              // 64*132 = 8448
    float* part_pw0 = ws + 8448;       // 64*128 = 8192
    float* part_dw1 = ws + 16640;      // 64*196 = 12544
    float* part_pw1 = ws + 29184;      // 64*64  = 4096
    float* part_dw2 = ws + 33280;      // 64*74  = 4736
    float* part_pw2 = ws + 38016;      // 64*42  = 2688  -> parts end 40704
    float* pw0raw = ws + 40704;        // 4*64*32*32 = 262144
    float* pw1raw = pw0raw + 262144;   // 4*32*64*64 = 524288
    float* bigA   = pw1raw + 524288;   // dw raw, up to 4*37*256*256 = 9699328

    hipMemsetAsync(ws, 0, 40704 * sizeof(float), stream);

    // ---- Level 0: C=66, 32x32, out 64 ----
    fused_dw_kernel<0, true><<<4 * 66 * 4, 256, 0, stream>>>(
        f1, nullptr, nullptr, nullptr, nullptr, 0.f, w0, bigA, part_dw0);
    pw_small_kernel<66, 64, 32, 16, 16><<<256, 256, 0, stream>>>(
        bigA, w0, part_dw0, g_dw0, b_dw0, 1.f / 4096.f, pw0raw, part_pw0, 4818, 594);
    // ---- Level 1: C=98, 64x64, out 32 ----
    fused_dw_kernel<1, true><<<4 * 98 * 16, 256, 0, stream>>>(
        f0, pw0raw, part_pw0, g_pw0, b_pw0, 1.f / 4096.f, w1, bigA, part_dw1);
    pw_small_kernel<98, 32, 64, 64, 4><<<256, 256, 0, stream>>>(
        bigA, w1, part_dw1, g_dw1, b_dw1, 1.f / 16384.f, pw1raw, part_pw1, 4018, 882);
    // ---- Level 2: C=37, 256x256, out 21 ----
    dw2_row_kernel<<<4 * 37 * 32, 256, 0, stream>>>(
        x_img, pw1raw, part_pw1, g_pw1, b_pw1, w2, bigA, part_dw2);
    pw2_kernel<<<256, 256, 0, stream>>>(bigA, w2, part_dw2, g_dw2, b_dw2, out, part_pw2);
    finalbn_kernel<<<1024, 256, 0, stream>>>(out, part_pw2, g_pw2, b_pw2);
}

// Round 7
// 147.469 us; speedup vs baseline: 1.3689x; 1.0288x over previous
//
#include <hip/hip_runtime.h>

#define EPS 1e-5f

__device__ __forceinline__ int reflect_idx(int i, int n) {
    if (i < 0) return -i;
    if (i >= n) return 2 * n - 2 - i;
    return i;
}

__device__ __forceinline__ float bilin(const float* __restrict__ pb, int Hp, float sy, float sx) {
    int y0 = (int)floorf(sy), x0 = (int)floorf(sx);
    float fy = sy - y0, fx = sx - x0;
    int y0c = min(max(y0, 0), Hp - 1), y1c = min(max(y0 + 1, 0), Hp - 1);
    int x0c = min(max(x0, 0), Hp - 1), x1c = min(max(x0 + 1, 0), Hp - 1);
    float v00 = pb[y0c * Hp + x0c], v01 = pb[y0c * Hp + x1c];
    float v10 = pb[y1c * Hp + x0c], v11 = pb[y1c * Hp + x1c];
    return v00 * (1 - fy) * (1 - fx) + v01 * (1 - fy) * fx
         + v10 * fy * (1 - fx) + v11 * fy * fx;
}

// Per-block redundant reduction of 64-slot striped partials -> (scale, shift) in LDS.
__device__ __forceinline__ void reduce_ss_lds(const float* __restrict__ part,
                                              const float* __restrict__ g,
                                              const float* __restrict__ bb,
                                              float* ss, int C, float invN, int tid) {
    for (int c = tid; c < C; c += 256) {
        float s1 = 0.f, s2 = 0.f;
#pragma unroll 8
        for (int s = 0; s < 64; ++s) {
            s1 += part[s * 2 * C + 2 * c];
            s2 += part[s * 2 * C + 2 * c + 1];
        }
        float m = s1 * invN;
        float var = s2 * invN - m * m;
        float sc = g[c] * rsqrtf(var + EPS);
        ss[2 * c] = sc;
        ss[2 * c + 1] = bb[c] - m * sc;
    }
}

// ---------------- Fused build + depthwise 3x3 + striped stats (levels 0/1) ----------------
template <int LEVEL, bool WRITE>
__global__ __launch_bounds__(256)
void fused_dw_kernel(const float* __restrict__ feat, const float* __restrict__ prev,
                     const float* __restrict__ part_prev, const float* __restrict__ g_prev,
                     const float* __restrict__ b_prev, float invN_prev,
                     const float* __restrict__ wsig,
                     float* __restrict__ out, float* __restrict__ part) {
    constexpr int C    = LEVEL == 0 ? 66 : LEVEL == 1 ? 98 : 37;
    constexpr int H    = LEVEL == 0 ? 32 : LEVEL == 1 ? 64 : 256;
    constexpr int TILE = LEVEL == 2 ? 32 : 16;
    constexpr int NT   = H / TILE;
    constexpr int PXPT = (TILE * TILE) / 256;
    constexpr int WC   = LEVEL == 0 ? 4818 : LEVEL == 1 ? 4018 : 1110;
    constexpr int NF   = LEVEL == 0 ? 64 : LEVEL == 1 ? 32 : 3;
    constexpr int Hp   = LEVEL == 1 ? 32 : 64;
    constexpr int Cp   = LEVEL == 1 ? 64 : 32;
    constexpr int P    = H / 8;
    constexpr float SC = LEVEL == 1 ? 0.5f : 0.25f;
    constexpr int HS   = TILE + 2;
    constexpr int PSS  = (LEVEL == 0) ? 2 : 2 * Cp;

    __shared__ float sh[HS * HS];
    __shared__ float pssl[PSS];
    int tid = threadIdx.x, bid = blockIdx.x;
    int tile = bid % (NT * NT);
    int c = (bid / (NT * NT)) % C;
    int b = bid / (NT * NT * C);
    int ty0 = (tile / NT) * TILE, tx0 = (tile % NT) * TILE;

    if constexpr (LEVEL != 0) {
        reduce_ss_lds(part_prev, g_prev, b_prev, pssl, Cp, invN_prev, tid);
        __syncthreads();
    }

    for (int i = tid; i < HS * HS; i += 256) {
        int h = reflect_idx(ty0 - 1 + i / HS, H);
        int w = reflect_idx(tx0 - 1 + i % HS, H);
        float val;
        if (c == 0)      val = -1.f + 2.f * w / (H - 1);
        else if (c == 1) val = -1.f + 2.f * h / (H - 1);
        else if (c < 2 + NF) val = feat[((size_t)(b * NF + c - 2) * H + h) * H + w];
        else {
            int o = c - 2 - NF;
            const float* pb = prev + (size_t)(b * Cp + o) * Hp * Hp;
            float raw = bilin(pb, Hp, (h + 0.5f) * SC - 0.5f, (w + 0.5f) * SC - 0.5f);
            val = raw * pssl[2 * o] + pssl[2 * o + 1];
        }
        sh[i] = val;
    }
    __syncthreads();

    float s1 = 0.f, s2 = 0.f;
    float* ob = out + (((size_t)(b * C + c)) * H + ty0) * H + tx0;
    float wreg[9];
    if constexpr (TILE == P) {
        const float* wb = wsig + ((size_t)(b * WC + c * 9)) * 64 + (ty0 / P) * 8 + (tx0 / P);
#pragma unroll
        for (int t = 0; t < 9; ++t) wreg[t] = wb[(size_t)t * 64];
    }
#pragma unroll
    for (int k = 0; k < PXPT; ++k) {
        int px = tid + k * 256;
        int tyy = px / TILE, txx = px % TILE;
        if constexpr (TILE != P) {
            int u = (ty0 + tyy) / P, vv = (tx0 + txx) / P;
            const float* wb = wsig + ((size_t)(b * WC + c * 9)) * 64 + u * 8 + vv;
#pragma unroll
            for (int t = 0; t < 9; ++t) wreg[t] = wb[(size_t)t * 64];
        }
        float acc = 0.f;
#pragma unroll
        for (int t = 0; t < 9; ++t)
            acc += wreg[t] * sh[(tyy + t / 3) * HS + txx + t % 3];
        if constexpr (WRITE) ob[tyy * H + txx] = acc;
        s1 += acc; s2 += acc * acc;
    }
#pragma unroll
    for (int off = 32; off; off >>= 1) {
        s1 += __shfl_xor(s1, off);
        s2 += __shfl_xor(s2, off);
    }
    __shared__ float r1[4], r2[4];
    int wave = tid >> 6;
    if ((tid & 63) == 0) { r1[wave] = s1; r2[wave] = s2; }
    __syncthreads();
    if (tid == 0) {
        int slot = bid & 63;
        atomicAdd(&part[slot * 2 * C + 2 * c],     r1[0] + r1[1] + r1[2] + r1[3]);
        atomicAdd(&part[slot * 2 * C + 2 * c + 1], r2[0] + r2[1] + r2[2] + r2[3]);
    }
}

// ---------------- Level-2 dw: column-per-thread, conflict-free LDS ----------------
// Block = (b, c, 8 rows). Thread t owns column t for all 8 rows.
__global__ __launch_bounds__(256)
void dw2_col_kernel(const float* __restrict__ ximg, const float* __restrict__ prev,
                    const float* __restrict__ part_prev, const float* __restrict__ g_prev,
                    const float* __restrict__ b_prev,
                    const float* __restrict__ wsig,
                    float* __restrict__ out, float* __restrict__ part) {
    const int C = 37, H = 256, W = 256, WC = 1110, Hp = 64, Cp = 32;
    const int S = 260;                    // LDS row stride (floats)
    __shared__ float sh[10 * S];          // rows ty0-1..ty0+8, cols -1..256 at offset+1
    __shared__ float pssl[64];
    __shared__ float lwv[72];
    __shared__ float r1[4], r2[4];

    int tid = threadIdx.x, bid = blockIdx.x;
    int rb = bid & 31;
    int c  = (bid >> 5) % C;
    int b  = bid / (32 * C);
    int ty0 = rb * 8;
    int u = rb >> 2;

    reduce_ss_lds(part_prev, g_prev, b_prev, pssl, Cp, 1.f / 16384.f, tid);
    if (tid < 72) {
        int v = tid / 9, t = tid % 9;
        lwv[tid] = wsig[((size_t)(b * WC + c * 9 + t)) * 64 + u * 8 + v];
    }
    __syncthreads();

    // stage built halo for this channel
    for (int i = tid; i < 10 * 258; i += 256) {
        int r = i / 258, wcol = i % 258 - 1;
        int h = reflect_idx(ty0 - 1 + r, H);
        int w = reflect_idx(wcol, W);
        float val;
        if (c == 0)      val = -1.f + 2.f * w / 255.f;
        else if (c == 1) val = -1.f + 2.f * h / 255.f;
        else if (c < 5)  val = ximg[((size_t)(b * 3 + c - 2) * H + h) * W + w];
        else {
            int o = c - 5;
            const float* pb = prev + (size_t)(b * Cp + o) * Hp * Hp;
            float raw = bilin(pb, Hp, (h + 0.5f) * 0.25f - 0.5f, (w + 0.5f) * 0.25f - 0.5f);
            val = raw * pssl[2 * o] + pssl[2 * o + 1];
        }
        sh[r * S + wcol + 1] = val;
    }
    __syncthreads();

    int t = tid;            // column 0..255
    int v = t >> 5;
    float wr[9];
#pragma unroll
    for (int tap = 0; tap < 9; ++tap) wr[tap] = lwv[v * 9 + tap];

    float px[8];
#pragma unroll
    for (int k = 0; k < 8; ++k) px[k] = 0.f;

#pragma unroll
    for (int r = 0; r < 10; ++r) {
        float L = sh[r * S + t];
        float M = sh[r * S + t + 1];
        float R = sh[r * S + t + 2];
#pragma unroll
        for (int dr = 0; dr < 3; ++dr) {
            int k = r - dr;
            if (k >= 0 && k < 8)
                px[k] += wr[dr * 3] * L + wr[dr * 3 + 1] * M + wr[dr * 3 + 2] * R;
        }
    }

    float* ob = out + (((size_t)(b * C + c)) * H + ty0) * W + t;
    float s1 = 0.f, s2 = 0.f;
#pragma unroll
    for (int k = 0; k < 8; ++k) {
        ob[k * W] = px[k];
        s1 += px[k]; s2 += px[k] * px[k];
    }
#pragma unroll
    for (int off = 32; off; off >>= 1) {
        s1 += __shfl_xor(s1, off);
        s2 += __shfl_xor(s2, off);
    }
    int wave = tid >> 6;
    if ((tid & 63) == 0) { r1[wave] = s1; r2[wave] = s2; }
    __syncthreads();
    if (tid == 0) {
        int slot = bid & 63;
        atomicAdd(&part[slot * 2 * C + 2 * c],     r1[0] + r1[1] + r1[2] + r1[3]);
        atomicAdd(&part[slot * 2 * C + 2 * c + 1], r2[0] + r2[1] + r2[2] + r2[3]);
    }
}

// ---------------- Pointwise 1x1, small levels, merged dw-stats reduce ----------------
template <int C, int ONC, int H, int PX_T, int OC_T>
__global__ __launch_bounds__(256)
void pw_small_kernel(const float* __restrict__ x, const float* __restrict__ wsig,
                     const float* __restrict__ part_in, const float* __restrict__ g,
                     const float* __restrict__ bb, float invN,
                     float* __restrict__ out, float* __restrict__ part, int WC, int ndw) {
    constexpr int P = H / 8;
    constexpr int OC_I = ONC / OC_T;
    __shared__ float lw[ONC * C];
    __shared__ float lx[C * PX_T];
    __shared__ float ssl[2 * C];
    int tid = threadIdx.x, bid = blockIdx.x;
    int uv = bid & 63, b = bid >> 6;
    int u = uv >> 3, v = uv & 7;

    const size_t wbase = ((size_t)b * WC + ndw) * 64 + uv;
    for (int i = tid; i < ONC * C; i += 256) lw[i] = wsig[wbase + (size_t)i * 64];
    reduce_ss_lds(part_in, g, bb, ssl, C, invN, tid);
    __syncthreads();

    for (int i = tid; i < C * PX_T; i += 256) {
        int c = i / PX_T, pxl = i % PX_T;
        int h = u * P + pxl / P, w = v * P + pxl % P;
        float xv = x[(((size_t)b * C + c) * H + h) * H + w];
        lx[i] = fminf(fmaxf(xv * ssl[2 * c] + ssl[2 * c + 1], 0.f), 6.f);
    }
    __syncthreads();

    int px_id = tid % PX_T, oc_id = tid / PX_T;
    int h = u * P + px_id / P, w = v * P + px_id % P;
    float acc[OC_I];
#pragma unroll
    for (int oi = 0; oi < OC_I; ++oi) acc[oi] = 0.f;
    for (int c = 0; c < C; ++c) {
        float xv = lx[c * PX_T + px_id];
#pragma unroll
        for (int oi = 0; oi < OC_I; ++oi)
            acc[oi] += lw[(oc_id * OC_I + oi) * C + c] * xv;
    }
    float* ob = out + (((size_t)b * ONC) * H + h) * H + w;
#pragma unroll
    for (int oi = 0; oi < OC_I; ++oi)
        ob[(size_t)(oc_id * OC_I + oi) * H * H] = acc[oi];

    constexpr int GROUP = (PX_T < 64) ? PX_T : 64;
    int lane = tid & 63;
    int slot = bid & 63;
#pragma unroll
    for (int oi = 0; oi < OC_I; ++oi) {
        float s1 = acc[oi], s2 = acc[oi] * acc[oi];
#pragma unroll
        for (int off = GROUP / 2; off; off >>= 1) {
            s1 += __shfl_xor(s1, off);
            s2 += __shfl_xor(s2, off);
        }
        if ((lane & (GROUP - 1)) == 0) {
            int o = oc_id * OC_I + oi;
            atomicAdd(&part[slot * 2 * ONC + 2 * o], s1);
            atomicAdd(&part[slot * 2 * ONC + 2 * o + 1], s2);
        }
    }
}

// ---------------- Pointwise 1x1 level 2: float4, merged dw2-stats reduce ----------------
__global__ __launch_bounds__(256)
void pw2_kernel(const float* __restrict__ x, const float* __restrict__ wsig,
                const float* __restrict__ part_in, const float* __restrict__ g,
                const float* __restrict__ bb,
                float* __restrict__ out, float* __restrict__ part) {
    const int C = 37, ONC = 21, H = 256, PATCH = 32, WC = 1110, NDW = 333;
    __shared__ float lw[ONC * C];
    __shared__ float ssl[2 * C];
    __shared__ float r1[4][ONC], r2[4][ONC];
    int tid = threadIdx.x, bid = blockIdx.x;
    int uv = bid & 63, b = bid >> 6;
    int y0 = (uv >> 3) * PATCH, x0 = (uv & 7) * PATCH;

    for (int i = tid; i < ONC * C; i += 256) lw[i] = wsig[((size_t)(b * WC + NDW) + i) * 64 + uv];
    reduce_ss_lds(part_in, g, bb, ssl, C, 1.f / 262144.f, tid);
    __syncthreads();

    int row = tid >> 3, col = (tid & 7) * 4;
    const float* xb = x + (((size_t)b * C) * H + y0 + row) * H + x0 + col;
    float4 acc[ONC];
#pragma unroll
    for (int o = 0; o < ONC; ++o) acc[o] = make_float4(0.f, 0.f, 0.f, 0.f);

    for (int c = 0; c < C; ++c) {
        float4 xv = *(const float4*)(xb + (size_t)c * H * H);
        float sc = ssl[2 * c], sb = ssl[2 * c + 1];
        xv.x = fminf(fmaxf(xv.x * sc + sb, 0.f), 6.f);
        xv.y = fminf(fmaxf(xv.y * sc + sb, 0.f), 6.f);
        xv.z = fminf(fmaxf(xv.z * sc + sb, 0.f), 6.f);
        xv.w = fminf(fmaxf(xv.w * sc + sb, 0.f), 6.f);
#pragma unroll
        for (int o = 0; o < ONC; ++o) {
            float wv = lw[o * C + c];
            acc[o].x += wv * xv.x;
            acc[o].y += wv * xv.y;
            acc[o].z += wv * xv.z;
            acc[o].w += wv * xv.w;
        }
    }
    float* ob = out + (((size_t)b * ONC) * H + y0 + row) * H + x0 + col;
#pragma unroll
    for (int o = 0; o < ONC; ++o) *(float4*)(ob + (size_t)o * H * H) = acc[o];

    int wave = tid >> 6, lane = tid & 63;
#pragma unroll
    for (int o = 0; o < ONC; ++o) {
        float s1 = acc[o].x + acc[o].y + acc[o].z + acc[o].w;
        float s2 = acc[o].x * acc[o].x + acc[o].y * acc[o].y
                 + acc[o].z * acc[o].z + acc[o].w * acc[o].w;
#pragma unroll
        for (int off = 32; off; off >>= 1) {
            s1 += __shfl_xor(s1, off);
            s2 += __shfl_xor(s2, off);
        }
        if (lane == 0) { r1[wave][o] = s1; r2[wave][o] = s2; }
    }
    __syncthreads();
    int slot = bid & 63;
    for (int o = tid; o < ONC; o += 256) {
        atomicAdd(&part[slot * 42 + 2 * o],     r1[0][o] + r1[1][o] + r1[2][o] + r1[3][o]);
        atomicAdd(&part[slot * 42 + 2 * o + 1], r2[0][o] + r2[1][o] + r2[2][o] + r2[3][o]);
    }
}

// ---------------- Final in-place BN (float4, grid-stride, merged pw2-stats reduce) ----------------
__global__ __launch_bounds__(256)
void finalbn_kernel(float* __restrict__ out, const float* __restrict__ part_in,
                    const float* __restrict__ g, const float* __restrict__ bb) {
    __shared__ float ssl[42];
    reduce_ss_lds(part_in, g, bb, ssl, 21, 1.f / 262144.f, threadIdx.x);
    __syncthreads();
    const int total4 = 4 * 21 * 256 * 256 / 4;
    for (int idx = blockIdx.x * 256 + threadIdx.x; idx < total4; idx += gridDim.x * 256) {
        int c = (idx / (256 * 256 / 4)) % 21;
        float4 v = ((float4*)out)[idx];
        float sc = ssl[2 * c], sb = ssl[2 * c + 1];
        v.x = v.x * sc + sb; v.y = v.y * sc + sb; v.z = v.z * sc + sb; v.w = v.w * sc + sb;
        ((float4*)out)[idx] = v;
    }
}

extern "C" void kernel_launch(void* const* d_in, const int* in_sizes, int n_in,
                              void* d_out, int out_size, void* d_ws, size_t ws_size,
                              hipStream_t stream) {
    const float* x_img = (const float*)d_in[0];
    const float* f0    = (const float*)d_in[1];
    const float* f1    = (const float*)d_in[2];
    const float* w0    = (const float*)d_in[3];
    const float* w1    = (const float*)d_in[4];
    const float* w2    = (const float*)d_in[5];
    const float* g_dw0 = (const float*)d_in[6],  *b_dw0 = (const float*)d_in[7];
    const float* g_pw0 = (const float*)d_in[8],  *b_pw0 = (const float*)d_in[9];
    const float* g_dw1 = (const float*)d_in[10], *b_dw1 = (const float*)d_in[11];
    const float* g_pw1 = (const float*)d_in[12], *b_pw1 = (const float*)d_in[13];
    const float* g_dw2 = (const float*)d_in[14], *b_dw2 = (const float*)d_in[15];
    const float* g_pw2 = (const float*)d_in[16], *b_pw2 = (const float*)d_in[17];
    float* out = (float*)d_out;
    float* ws = (float*)d_ws;

    // workspace layout (floats)
    float* part_dw0 = ws;              // 64*132 = 8448
    float* part_pw0 = ws + 8448;       // 64*128 = 8192
    float* part_dw1 = ws + 16640;      // 64*196 = 12544
    float* part_pw1 = ws + 29184;      // 64*64  = 4096
    float* part_dw2 = ws + 33280;      // 64*74  = 4736
    float* part_pw2 = ws + 38016;      // 64*42  = 2688  -> parts end 40704
    float* pw0raw = ws + 40704;        // 4*64*32*32 = 262144
    float* pw1raw = pw0raw + 262144;   // 4*32*64*64 = 524288
    float* bigA   = pw1raw + 524288;   // dw raw, up to 4*37*256*256 = 9699328

    hipMemsetAsync(ws, 0, 40704 * sizeof(float), stream);

    // ---- Level 0: C=66, 32x32, out 64 ----
    fused_dw_kernel<0, true><<<4 * 66 * 4, 256, 0, stream>>>(
        f1, nullptr, nullptr, nullptr, nullptr, 0.f, w0, bigA, part_dw0);
    pw_small_kernel<66, 64, 32, 16, 16><<<256, 256, 0, stream>>>(
        bigA, w0, part_dw0, g_dw0, b_dw0, 1.f / 4096.f, pw0raw, part_pw0, 4818, 594);
    // ---- Level 1: C=98, 64x64, out 32 ----
    fused_dw_kernel<1, true><<<4 * 98 * 16, 256, 0, stream>>>(
        f0, pw0raw, part_pw0, g_pw0, b_pw0, 1.f / 4096.f, w1, bigA, part_dw1);
    pw_small_kernel<98, 32, 64, 64, 4><<<256, 256, 0, stream>>>(
        bigA, w1, part_dw1, g_dw1, b_dw1, 1.f / 16384.f, pw1raw, part_pw1, 4018, 882);
    // ---- Level 2: C=37, 256x256, out 21 ----
    dw2_col_kernel<<<4 * 37 * 32, 256, 0, stream>>>(
        x_img, pw1raw, part_pw1, g_pw1, b_pw1, w2, bigA, part_dw2);
    pw2_kernel<<<256, 256, 0, stream>>>(bigA, w2, part_dw2, g_dw2, b_dw2, out, part_pw2);
    finalbn_kernel<<<1024, 256, 0, stream>>>(out, part_pw2, g_pw2, b_pw2);
}